// Round 29
// baseline (171.339 us; speedup 1.0000x reference)
//
#include <hip/hip_runtime.h>
#include <hip/hip_bf16.h>
#include <hip/hip_fp16.h>

// Problem constants (fixed by the reference)
#define E    256
#define NH   8
#define NL   3
#define NP   4
#define HD   32
#define LQ   13125   // = Lv = 10000 + 2500 + 625

typedef short bf16x8 __attribute__((ext_vector_type(8)));
typedef _Float16 f16x8 __attribute__((ext_vector_type(8)));
typedef float f32x4  __attribute__((ext_vector_type(4)));

// round-to-nearest-even fp32 -> bf16 (as ushort bits)
__device__ __forceinline__ ushort f2bf(float x) {
  uint u = __float_as_uint(x);
  uint r = (u + 0x7fffu + ((u >> 16) & 1u)) >> 16;
  return (ushort)r;
}
__device__ __forceinline__ float bf2f(ushort u) {
  return __uint_as_float((uint)u << 16);
}
__device__ __forceinline__ ushort f2h(float x) {
  return __half_as_ushort(__float2half(x));
}
__device__ __forceinline__ __half2 u2h2(uint u) {
  union { uint u; __half2 h; } c; c.u = u; return c.h;
}
__device__ __forceinline__ uint h22u(__half2 h) {
  union { uint u; __half2 h; } c; c.h = h; return c.u;
}

__device__ __forceinline__ void gl_lds16(const ushort* g, ushort* l) {
  __builtin_amdgcn_global_load_lds(
      (const __attribute__((address_space(1))) void*)g,
      (__attribute__((address_space(3))) void*)l, 16, 0, 0);
}

// convert 8 consecutive fp32 -> bf16x8 (for reg-staged A conversion)
__device__ __forceinline__ bf16x8 cvt8(const float* p) {
  const float4 a = *(const float4*)p;
  const float4 b = *(const float4*)(p + 4);
  bf16x8 r;
  r[0] = (short)f2bf(a.x); r[1] = (short)f2bf(a.y);
  r[2] = (short)f2bf(a.z); r[3] = (short)f2bf(a.w);
  r[4] = (short)f2bf(b.x); r[5] = (short)f2bf(b.y);
  r[6] = (short)f2bf(b.z); r[7] = (short)f2bf(b.w);
  return r;
}

// ---------------------------------------------------------------------------
// Value projection (round-19 proven): 128x256 tile, 512 threads (8 waves,
// 2x4 of 64x64).  fp32 A -> bf16 reg-staged; bf16 MFMA; fp16 head-major out.
// ---------------------------------------------------------------------------
__global__ __launch_bounds__(512) void gemm_wide_v(
    const float* __restrict__ A32, const ushort* __restrict__ B_,
    const float* __restrict__ bias, ushort* __restrict__ Cf16, int M) {
  __shared__ ushort As[4096];   // [128][32]
  __shared__ ushort Bs[8192];   // [256][32]
  const int tid = threadIdx.x;
  const int lane = tid & 63;
  const int wid = tid >> 6;
  const int wm = wid >> 2, wn = wid & 3;
  const int r0 = blockIdx.x * 128;
  const int l15 = lane & 15;
  const int lhi = lane >> 4;

  f32x4 acc[4][4] = {};

  for (int kk = 0; kk < 256; kk += 32) {
    {
      const int arow = min(r0 + (tid >> 2), M - 1);
      *(bf16x8*)&As[tid * 8] =
          cvt8(A32 + (size_t)arow * 256 + kk + (tid & 3) * 8);
    }
#pragma unroll
    for (int rr = 0; rr < 2; ++rr) {
      const int u = rr * 512 + tid;
      const int brow = u >> 2;
      gl_lds16(B_ + (size_t)brow * 256 + kk + (u & 3) * 8,
               Bs + rr * 4096 + wid * 512);
    }
    __syncthreads();

    bf16x8 af[4], bf[4];
#pragma unroll
    for (int mi = 0; mi < 4; ++mi)
      af[mi] = *(const bf16x8*)&As[(wm * 64 + mi * 16 + l15) * 32 + lhi * 8];
#pragma unroll
    for (int ni = 0; ni < 4; ++ni)
      bf[ni] = *(const bf16x8*)&Bs[(wn * 64 + ni * 16 + l15) * 32 + lhi * 8];
#pragma unroll
    for (int mi = 0; mi < 4; ++mi)
#pragma unroll
      for (int ni = 0; ni < 4; ++ni)
        acc[mi][ni] = __builtin_amdgcn_mfma_f32_16x16x32_bf16(
            af[mi], bf[ni], acc[mi][ni], 0, 0, 0);
    __syncthreads();
  }

#pragma unroll
  for (int ni = 0; ni < 4; ++ni) {
    const int col = wn * 64 + ni * 16 + l15;
    const float bb = bias[col];
    const int h = col >> 5, d = col & 31;
#pragma unroll
    for (int mi = 0; mi < 4; ++mi) {
      const int rowb = r0 + wm * 64 + mi * 16 + lhi * 4;
#pragma unroll
      for (int r = 0; r < 4; ++r) {
        const int row = rowb + r;
        if (row >= M) continue;
        const int bidx = row / LQ, pos = row - bidx * LQ;
        Cf16[((size_t)(bidx * NH + h) * LQ + pos) * HD + d] =
            f2h(acc[mi][ni][r] + bb);
      }
    }
  }
}

// ---------------------------------------------------------------------------
// Fused offatt GEMM + finalize_pack, DOUBLE-PANEL epilogue (round-28 proven):
// 512 threads, 128 rows x 288 cols; 2 rounds of {4 waves write 2 panels
// concurrently -> 512-thread pack}.  Record d0 = (loff+idx00)*64 | dx<<20 |
// (y1c!=y0c)<<21; d1/d2 fp16 weight pairs.
// ---------------------------------------------------------------------------
__global__ __launch_bounds__(512) void gemm_q_pack(
    const float* __restrict__ A32, const ushort* __restrict__ B_,
    const float* __restrict__ bias, const float* __restrict__ ref,
    uint* __restrict__ samp, int M) {
  __shared__ __align__(16) char ldsbuf[74 * 1024];
  ushort* As = (ushort*)ldsbuf;              // [128][32]
  ushort* Bs = (ushort*)(ldsbuf + 8192);     // [288][32]
  float* panel0 = (float*)ldsbuf;            // [32][289]
  float* panel1 = (float*)(ldsbuf + 37 * 1024);  // [32][289]

  const int tid = threadIdx.x;
  const int lane = tid & 63;
  const int wid = tid >> 6;
  const int rg = wid >> 1;   // row group (32 rows)
  const int cg = wid & 1;    // col group (144 cols)
  const int r0 = blockIdx.x * 128;
  const int l15 = lane & 15;
  const int lhi = lane >> 4;

  f32x4 acc[2][9] = {};

  for (int kk = 0; kk < 256; kk += 32) {
    {
      const int arow = min(r0 + (tid >> 2), M - 1);
      *(bf16x8*)&As[tid * 8] =
          cvt8(A32 + (size_t)arow * 256 + kk + (tid & 3) * 8);
    }
#pragma unroll
    for (int rr = 0; rr < 3; ++rr) {
      const int u = rr * 512 + tid;
      if (u < 1152)
        gl_lds16(B_ + (size_t)(u >> 2) * 256 + kk + (u & 3) * 8,
                 Bs + (u >> 2) * 32 + (u & 3) * 8);
    }
    __syncthreads();

    bf16x8 af[2], bf[9];
#pragma unroll
    for (int mi = 0; mi < 2; ++mi)
      af[mi] = *(const bf16x8*)&As[(rg * 32 + mi * 16 + l15) * 32 + lhi * 8];
#pragma unroll
    for (int ni = 0; ni < 9; ++ni)
      bf[ni] = *(const bf16x8*)&Bs[(cg * 144 + ni * 16 + l15) * 32 + lhi * 8];
#pragma unroll
    for (int mi = 0; mi < 2; ++mi)
#pragma unroll
      for (int ni = 0; ni < 9; ++ni)
        acc[mi][ni] = __builtin_amdgcn_mfma_f32_16x16x32_bf16(
            af[mi], bf[ni], acc[mi][ni], 0, 0, 0);
    __syncthreads();
  }

  const float S_[3] = {100.f, 50.f, 25.f};
  const int Wl_[3] = {100, 50, 25};
  const int loff_[3] = {0, 10000, 12500};
#pragma unroll
  for (int cc = 0; cc < 2; ++cc) {
    if ((rg >> 1) == cc) {
      float* pan = (rg & 1) ? panel1 : panel0;
#pragma unroll
      for (int mi = 0; mi < 2; ++mi)
#pragma unroll
        for (int ni = 0; ni < 9; ++ni) {
          const int col = cg * 144 + ni * 16 + l15;
          const float bb = bias[col];
          const int rl = mi * 16 + lhi * 4;
#pragma unroll
          for (int r = 0; r < 4; ++r)
            pan[(rl + r) * 289 + col] = acc[mi][ni][r] + bb;
        }
    }
    __syncthreads();
    {
      const int rr = tid >> 3;          // 0..63 (rows within this round)
      const int h = tid & 7;
      const int g = r0 + cc * 64 + rr;
      if (g < M) {
        const float* rg_ = (rr < 32) ? &panel0[rr * 289]
                                     : &panel1[(rr - 32) * 289];
        float xy[24], lg[12];
#pragma unroll
        for (int j = 0; j < 24; ++j) xy[j] = rg_[h * 24 + j];
#pragma unroll
        for (int j = 0; j < 12; ++j) lg[j] = rg_[192 + h * 12 + j];
        float rx[3], ry[3];
#pragma unroll
        for (int l = 0; l < 3; ++l) {
          rx[l] = ref[(size_t)g * 6 + l * 2 + 0];
          ry[l] = ref[(size_t)g * 6 + l * 2 + 1];
        }
        float m = lg[0];
#pragma unroll
        for (int j = 1; j < 12; ++j) m = fmaxf(m, lg[j]);
        float e[12], s = 0.f;
#pragma unroll
        for (int j = 0; j < 12; ++j) { e[j] = __expf(lg[j] - m); s += e[j]; }
        const float inv = 1.f / s;

        uint out[36];
#pragma unroll
        for (int l = 0; l < 3; ++l) {
          const int Wl = Wl_[l];
#pragma unroll
          for (int p = 0; p < 4; ++p) {
            const int j = l * 4 + p;
            const float x = rx[l] * S_[l] + xy[l * 8 + p * 2 + 0] - 0.5f;
            const float y = ry[l] * S_[l] + xy[l * 8 + p * 2 + 1] - 0.5f;
            const float w = e[j] * inv;
            const float fx = floorf(x), fy = floorf(y);
            const int x0 = (int)fx, y0 = (int)fy;
            const float wx1 = x - fx, wy1 = y - fy;
            const float wx0 = 1.f - wx1, wy0 = 1.f - wy1;
            const int x0c = min(max(x0, 0), Wl - 1);
            const int x1c = min(max(x0 + 1, 0), Wl - 1);
            const int y0c = min(max(y0, 0), Wl - 1);
            const int y1c = min(max(y0 + 1, 0), Wl - 1);
            const float vx0 = (x0 >= 0 && x0 < Wl) ? wx0 : 0.f;
            const float vx1 = (x0 + 1 >= 0 && x0 + 1 < Wl) ? wx1 : 0.f;
            const float vy0 = (y0 >= 0 && y0 < Wl) ? wy0 : 0.f;
            const float vy1 = (y0 + 1 >= 0 && y0 + 1 < Wl) ? wy1 : 0.f;
            const uint base = (uint)(loff_[l] + y0c * Wl + x0c) * 64u;
            out[j * 3 + 0] = base | ((uint)(x1c - x0c) << 20)
                                  | ((uint)(y1c != y0c) << 21);
            out[j * 3 + 1] = (uint)f2h(w * vy0 * vx0) | ((uint)f2h(w * vy0 * vx1) << 16);
            out[j * 3 + 2] = (uint)f2h(w * vy1 * vx0) | ((uint)f2h(w * vy1 * vx1) << 16);
          }
        }
        uint4* o4 = (uint4*)(samp + (size_t)g * 288 + h * 36);
#pragma unroll
        for (int i = 0; i < 9; ++i)
          o4[i] = make_uint4(out[i * 4 + 0], out[i * 4 + 1],
                             out[i * 4 + 2], out[i * 4 + 3]);
      }
    }
    __syncthreads();
  }
}

// ---------------------------------------------------------------------------
// Output projection (round-19 proven): 128x256 tile, 512 threads, fp16 A via
// global_load_lds, fp16 B (WoT), f16 MFMA, fp32 C.
// ---------------------------------------------------------------------------
__global__ __launch_bounds__(512) void gemm_wide_o(
    const ushort* __restrict__ A16, const ushort* __restrict__ B_,
    const float* __restrict__ bias, float* __restrict__ C, int M) {
  __shared__ ushort As[4096];   // [128][32]
  __shared__ ushort Bs[8192];   // [256][32]
  const int tid = threadIdx.x;
  const int lane = tid & 63;
  const int wid = tid >> 6;
  const int wm = wid >> 2, wn = wid & 3;
  const int r0 = blockIdx.x * 128;
  const int l15 = lane & 15;
  const int lhi = lane >> 4;

  f32x4 acc[4][4] = {};

  for (int kk = 0; kk < 256; kk += 32) {
    {
      const int arow = min(r0 + wid * 16 + (lane >> 2), M - 1);
      gl_lds16(A16 + (size_t)arow * 256 + kk + (lane & 3) * 8,
               As + wid * 512);
    }
#pragma unroll
    for (int rr = 0; rr < 2; ++rr) {
      const int u = rr * 512 + tid;
      const int brow = u >> 2;
      gl_lds16(B_ + (size_t)brow * 256 + kk + (u & 3) * 8,
               Bs + rr * 4096 + wid * 512);
    }
    __syncthreads();

    f16x8 af[4], bf[4];
#pragma unroll
    for (int mi = 0; mi < 4; ++mi)
      af[mi] = *(const f16x8*)&As[(wm * 64 + mi * 16 + l15) * 32 + lhi * 8];
#pragma unroll
    for (int ni = 0; ni < 4; ++ni)
      bf[ni] = *(const f16x8*)&Bs[(wn * 64 + ni * 16 + l15) * 32 + lhi * 8];
#pragma unroll
    for (int mi = 0; mi < 4; ++mi)
#pragma unroll
      for (int ni = 0; ni < 4; ++ni)
        acc[mi][ni] = __builtin_amdgcn_mfma_f32_16x16x32_f16(
            af[mi], bf[ni], acc[mi][ni], 0, 0, 0);
    __syncthreads();
  }

#pragma unroll
  for (int ni = 0; ni < 4; ++ni) {
    const int col = wn * 64 + ni * 16 + l15;
    const float bb = bias[col];
#pragma unroll
    for (int mi = 0; mi < 4; ++mi) {
      const int rowb = r0 + wm * 64 + mi * 16 + lhi * 4;
#pragma unroll
      for (int r = 0; r < 4; ++r) {
        const int row = rowb + r;
        if (row < M) C[(size_t)row * 256 + col] = acc[mi][ni][r] + bb;
      }
    }
  }
}

// ---------------------------------------------------------------------------
// One-shot weight prep: transpose; Wv/Wc as bf16, Wo as FP16.
// ---------------------------------------------------------------------------
__global__ __launch_bounds__(256) void convert_W(
    const float* __restrict__ Wv, const float* __restrict__ Woff,
    const float* __restrict__ Watt, const float* __restrict__ Wo,
    const float* __restrict__ boff, const float* __restrict__ batt,
    ushort* __restrict__ WvT, ushort* __restrict__ WcT,
    ushort* __restrict__ WoT, float* __restrict__ bias288) {
  const int t = blockIdx.x * 256 + threadIdx.x;
  if (t < 256 * 256) {
    const int n = t >> 8, k = t & 255;
    WvT[t] = f2bf(Wv[k * 256 + n]);
    WoT[t] = f2h(Wo[k * 256 + n]);
  }
  if (t < 288 * 256) {
    const int n = t >> 8, k = t & 255;
    const float w = (n < 192) ? Woff[k * 192 + n] : Watt[k * 96 + (n - 192)];
    WcT[t] = f2bf(w);
  }
  if (t < 288) bias288[t] = (t < 192) ? boff[t] : batt[t - 192];
}

// ---------------------------------------------------------------------------
// v11 sample body: SQ compile-time parity; byte-offset record decode;
// weight extract+broadcast via single v_perm_b32 (selector precomputed:
// 0x01000100 replicates fp16 lo half, 0x03020302 the hi half).
// ---------------------------------------------------------------------------
template <int SQ>
__device__ __forceinline__ void deform_body(
    const uint* __restrict__ rec, const char* __restrict__ vb, int xs,
    uint wsel, __half2& A0, __half2& A1, __half2& A2, __half2& A3) {
  const uint LB_[3] = {6400u, 3200u, 1600u};  // Wl*HD*2 per level
#pragma unroll
  for (int t = 0; t < 6; ++t) {
    const int j = 2 * t + SQ;                 // compile-time constant
    const uint d0 = rec[j * 3 + 0];
    const uint d1 = rec[j * 3 + 1];
    const uint d2 = rec[j * 3 + 2];
    const uint base = d0 & 0xFFFFFu;
    const uint offA = base + (xs ? ((d0 >> 14) & 64u) : 0u);
    const uint offB = offA + ((d0 & (1u << 21)) ? LB_[j >> 2] : 0u);
    const uint4 c0 = *(const uint4*)(vb + offA);
    const uint4 c1 = *(const uint4*)(vb + offB);
    const __half2 w0 = u2h2(__builtin_amdgcn_perm(d1, d1, wsel));
    const __half2 w1 = u2h2(__builtin_amdgcn_perm(d2, d2, wsel));
    A0 = __hfma2(w0, u2h2(c0.x), A0);
    A1 = __hfma2(w0, u2h2(c0.y), A1);
    A2 = __hfma2(w0, u2h2(c0.z), A2);
    A3 = __hfma2(w0, u2h2(c0.w), A3);
    A0 = __hfma2(w1, u2h2(c1.x), A0);
    A1 = __hfma2(w1, u2h2(c1.y), A1);
    A2 = __hfma2(w1, u2h2(c1.z), A2);
    A3 = __hfma2(w1, u2h2(c1.w), A3);
  }
}

// ---------------------------------------------------------------------------
// Bilinear sampling v11 = v10 structure (16 lanes per (g,h), LDS-staged
// records, parity-template bodies, byte-offset decode) + v_perm weight
// broadcast.  Block = 16 queries x one pair; XCD: blockIdx = qchunk*32+pair.
// ---------------------------------------------------------------------------
__global__ __launch_bounds__(256) void deform_packed(
    const ushort* __restrict__ vbf, const uint* __restrict__ samp,
    ushort* __restrict__ mid, int nq) {
  __shared__ __align__(16) uint recs[16][36];
  const int tid = threadIdx.x;
  const int pair = blockIdx.x & 31;          // b*8 + h
  const int qc = blockIdx.x >> 5;
  const int h = pair & 7;
  const int b = pair >> 3;
  const int q0 = qc * 16;

  // cooperative record staging: 144 uint4 (16 queries x 9)
  for (int i = tid; i < 144; i += 256) {
    const int qi = i / 9, di = (i - qi * 9) * 4;
    const int q = q0 + qi;
    if (q < nq)
      *(uint4*)&recs[qi][di] =
          *(const uint4*)&samp[((size_t)(b * nq + q)) * 288 + h * 36 + di];
  }
  __syncthreads();

  const int qi = tid >> 4;
  const int q = q0 + qi;
  if (q >= nq) return;
  const int lane16 = tid & 15;
  const int sq = lane16 >> 3;                // sample parity (0/1)
  const int xs = (lane16 >> 2) & 1;          // x-side
  const int cq = lane16 & 3;                 // channel quad (8 ch)
  const int g = b * nq + q;
  const uint wsel = xs ? 0x03020302u : 0x01000100u;

  const char* vb = (const char*)(vbf + ((size_t)pair * nq) * HD + cq * 8);
  const uint* rec = recs[qi];

  __half2 A0 = __float2half2_rn(0.f), A1 = A0, A2 = A0, A3 = A0;
  if (sq == 0) deform_body<0>(rec, vb, xs, wsel, A0, A1, A2, A3);
  else         deform_body<1>(rec, vb, xs, wsel, A0, A1, A2, A3);

  // merge sample parities (lane^8), then x-sides (lane^4)
  A0 = __hadd2(A0, u2h2(__shfl_xor(h22u(A0), 8)));
  A1 = __hadd2(A1, u2h2(__shfl_xor(h22u(A1), 8)));
  A2 = __hadd2(A2, u2h2(__shfl_xor(h22u(A2), 8)));
  A3 = __hadd2(A3, u2h2(__shfl_xor(h22u(A3), 8)));
  A0 = __hadd2(A0, u2h2(__shfl_xor(h22u(A0), 4)));
  A1 = __hadd2(A1, u2h2(__shfl_xor(h22u(A1), 4)));
  A2 = __hadd2(A2, u2h2(__shfl_xor(h22u(A2), 4)));
  A3 = __hadd2(A3, u2h2(__shfl_xor(h22u(A3), 4)));

  if ((lane16 >> 2) == 0) {  // sq == 0 && xs == 0
    uint4 o;
    o.x = h22u(A0); o.y = h22u(A1); o.z = h22u(A2); o.w = h22u(A3);
    *(uint4*)&mid[(size_t)g * E + h * HD + cq * 8] = o;
  }
}

// ---------------------------------------------------------------------------
extern "C" void kernel_launch(void* const* d_in, const int* in_sizes, int n_in,
                              void* d_out, int out_size, void* d_ws, size_t ws_size,
                              hipStream_t stream) {
  const float* query = (const float*)d_in[0];
  const float* refpt = (const float*)d_in[1];
  const float* value = (const float*)d_in[2];
  const float* Wv   = (const float*)d_in[4];
  const float* bv   = (const float*)d_in[5];
  const float* Woff = (const float*)d_in[6];
  const float* boff = (const float*)d_in[7];
  const float* Watt = (const float*)d_in[8];
  const float* batt = (const float*)d_in[9];
  const float* Wo   = (const float*)d_in[10];
  const float* bo   = (const float*)d_in[11];

  const int M = in_sizes[0] / E;  // B * Lq = 52500
  const int nq = LQ;              // queries per batch
  const int nb = M / nq;          // B = 4

  // workspace layout (~90 MB)
  float* wsf   = (float*)d_ws;
  float* raw   = wsf;                         // M*288 dwords: packed samples
  float* b288  = raw + (size_t)M * 288;       // 288
  ushort* mid  = (ushort*)(b288 + 288);       // M*256 fp16
  ushort* vbf  = mid + (size_t)M * 256;       // M*256 fp16
  ushort* wvT  = vbf + (size_t)M * 256;       // 65536 bf16
  ushort* woT  = wvT + 65536;                 // 65536 fp16
  ushort* wcT  = woT + 65536;                 // 73728 bf16

  const int gridM = (M + 127) / 128;

  // 0. weight prep
  convert_W<<<288, 256, 0, stream>>>(Wv, Woff, Watt, Wo, boff, batt,
                                     wvT, wcT, woT, b288);
  // 1. value projection (512-thr wide, round-19 proven) -> vbf (fp16)
  gemm_wide_v<<<gridM, 512, 0, stream>>>(value, wvT, bv, vbf, M);
  // 2. fused offsets+attention GEMM + double-panel pack -> samp
  gemm_q_pack<<<gridM, 512, 0, stream>>>(
      query, wcT, b288, refpt, (uint*)raw, M);
  // 3. deformable bilinear sampling v11 (v_perm weight broadcast)
  const int qchunks = (nq + 15) / 16;
  deform_packed<<<qchunks * 32, 256, 0, stream>>>(
      vbf, (const uint*)raw, mid, nq);
  // 4. output projection (512-thr wide, round-19 proven) -> d_out (fp32)
  gemm_wide_o<<<gridM, 512, 0, stream>>>(mid, woT, bo, (float*)d_out, M);
}

// Round 30
// 168.520 us; speedup vs baseline: 1.0167x; 1.0167x over previous
//
#include <hip/hip_runtime.h>
#include <hip/hip_bf16.h>
#include <hip/hip_fp16.h>

// Problem constants (fixed by the reference)
#define E    256
#define NH   8
#define NL   3
#define NP   4
#define HD   32
#define LQ   13125   // = Lv = 10000 + 2500 + 625

typedef short bf16x8 __attribute__((ext_vector_type(8)));
typedef _Float16 f16x8 __attribute__((ext_vector_type(8)));
typedef float f32x4  __attribute__((ext_vector_type(4)));

// round-to-nearest-even fp32 -> bf16 (as ushort bits)
__device__ __forceinline__ ushort f2bf(float x) {
  uint u = __float_as_uint(x);
  uint r = (u + 0x7fffu + ((u >> 16) & 1u)) >> 16;
  return (ushort)r;
}
__device__ __forceinline__ float bf2f(ushort u) {
  return __uint_as_float((uint)u << 16);
}
__device__ __forceinline__ ushort f2h(float x) {
  return __half_as_ushort(__float2half(x));
}
__device__ __forceinline__ __half2 u2h2(uint u) {
  union { uint u; __half2 h; } c; c.u = u; return c.h;
}
__device__ __forceinline__ uint h22u(__half2 h) {
  union { uint u; __half2 h; } c; c.h = h; return c.u;
}

__device__ __forceinline__ void gl_lds16(const ushort* g, ushort* l) {
  __builtin_amdgcn_global_load_lds(
      (const __attribute__((address_space(1))) void*)g,
      (__attribute__((address_space(3))) void*)l, 16, 0, 0);
}

// convert 8 consecutive fp32 -> bf16x8 (for reg-staged A conversion)
__device__ __forceinline__ bf16x8 cvt8(const float* p) {
  const float4 a = *(const float4*)p;
  const float4 b = *(const float4*)(p + 4);
  bf16x8 r;
  r[0] = (short)f2bf(a.x); r[1] = (short)f2bf(a.y);
  r[2] = (short)f2bf(a.z); r[3] = (short)f2bf(a.w);
  r[4] = (short)f2bf(b.x); r[5] = (short)f2bf(b.y);
  r[6] = (short)f2bf(b.z); r[7] = (short)f2bf(b.w);
  return r;
}

// ---------------------------------------------------------------------------
// Value projection (round-19 proven): 128x256 tile, 512 threads (8 waves,
// 2x4 of 64x64).  fp32 A -> bf16 reg-staged; bf16 MFMA; fp16 head-major out.
// ---------------------------------------------------------------------------
__global__ __launch_bounds__(512) void gemm_wide_v(
    const float* __restrict__ A32, const ushort* __restrict__ B_,
    const float* __restrict__ bias, ushort* __restrict__ Cf16, int M) {
  __shared__ ushort As[4096];   // [128][32]
  __shared__ ushort Bs[8192];   // [256][32]
  const int tid = threadIdx.x;
  const int lane = tid & 63;
  const int wid = tid >> 6;
  const int wm = wid >> 2, wn = wid & 3;
  const int r0 = blockIdx.x * 128;
  const int l15 = lane & 15;
  const int lhi = lane >> 4;

  f32x4 acc[4][4] = {};

  for (int kk = 0; kk < 256; kk += 32) {
    {
      const int arow = min(r0 + (tid >> 2), M - 1);
      *(bf16x8*)&As[tid * 8] =
          cvt8(A32 + (size_t)arow * 256 + kk + (tid & 3) * 8);
    }
#pragma unroll
    for (int rr = 0; rr < 2; ++rr) {
      const int u = rr * 512 + tid;
      const int brow = u >> 2;
      gl_lds16(B_ + (size_t)brow * 256 + kk + (u & 3) * 8,
               Bs + rr * 4096 + wid * 512);
    }
    __syncthreads();

    bf16x8 af[4], bf[4];
#pragma unroll
    for (int mi = 0; mi < 4; ++mi)
      af[mi] = *(const bf16x8*)&As[(wm * 64 + mi * 16 + l15) * 32 + lhi * 8];
#pragma unroll
    for (int ni = 0; ni < 4; ++ni)
      bf[ni] = *(const bf16x8*)&Bs[(wn * 64 + ni * 16 + l15) * 32 + lhi * 8];
#pragma unroll
    for (int mi = 0; mi < 4; ++mi)
#pragma unroll
      for (int ni = 0; ni < 4; ++ni)
        acc[mi][ni] = __builtin_amdgcn_mfma_f32_16x16x32_bf16(
            af[mi], bf[ni], acc[mi][ni], 0, 0, 0);
    __syncthreads();
  }

#pragma unroll
  for (int ni = 0; ni < 4; ++ni) {
    const int col = wn * 64 + ni * 16 + l15;
    const float bb = bias[col];
    const int h = col >> 5, d = col & 31;
#pragma unroll
    for (int mi = 0; mi < 4; ++mi) {
      const int rowb = r0 + wm * 64 + mi * 16 + lhi * 4;
#pragma unroll
      for (int r = 0; r < 4; ++r) {
        const int row = rowb + r;
        if (row >= M) continue;
        const int bidx = row / LQ, pos = row - bidx * LQ;
        Cf16[((size_t)(bidx * NH + h) * LQ + pos) * HD + d] =
            f2h(acc[mi][ni][r] + bb);
      }
    }
  }
}

// ---------------------------------------------------------------------------
// Fused offatt GEMM + finalize_pack, DOUBLE-PANEL epilogue (round-28 proven):
// 512 threads, 128 rows x 288 cols; 2 rounds of {4 waves write 2 panels
// concurrently -> 512-thread pack}.  Record d0 = (loff+idx00)*64 | dx<<20 |
// (y1c!=y0c)<<21; d1/d2 fp16 weight pairs.
// ---------------------------------------------------------------------------
__global__ __launch_bounds__(512) void gemm_q_pack(
    const float* __restrict__ A32, const ushort* __restrict__ B_,
    const float* __restrict__ bias, const float* __restrict__ ref,
    uint* __restrict__ samp, int M) {
  __shared__ __align__(16) char ldsbuf[74 * 1024];
  ushort* As = (ushort*)ldsbuf;              // [128][32]
  ushort* Bs = (ushort*)(ldsbuf + 8192);     // [288][32]
  float* panel0 = (float*)ldsbuf;            // [32][289]
  float* panel1 = (float*)(ldsbuf + 37 * 1024);  // [32][289]

  const int tid = threadIdx.x;
  const int lane = tid & 63;
  const int wid = tid >> 6;
  const int rg = wid >> 1;   // row group (32 rows)
  const int cg = wid & 1;    // col group (144 cols)
  const int r0 = blockIdx.x * 128;
  const int l15 = lane & 15;
  const int lhi = lane >> 4;

  f32x4 acc[2][9] = {};

  for (int kk = 0; kk < 256; kk += 32) {
    {
      const int arow = min(r0 + (tid >> 2), M - 1);
      *(bf16x8*)&As[tid * 8] =
          cvt8(A32 + (size_t)arow * 256 + kk + (tid & 3) * 8);
    }
#pragma unroll
    for (int rr = 0; rr < 3; ++rr) {
      const int u = rr * 512 + tid;
      if (u < 1152)
        gl_lds16(B_ + (size_t)(u >> 2) * 256 + kk + (u & 3) * 8,
                 Bs + (u >> 2) * 32 + (u & 3) * 8);
    }
    __syncthreads();

    bf16x8 af[2], bf[9];
#pragma unroll
    for (int mi = 0; mi < 2; ++mi)
      af[mi] = *(const bf16x8*)&As[(rg * 32 + mi * 16 + l15) * 32 + lhi * 8];
#pragma unroll
    for (int ni = 0; ni < 9; ++ni)
      bf[ni] = *(const bf16x8*)&Bs[(cg * 144 + ni * 16 + l15) * 32 + lhi * 8];
#pragma unroll
    for (int mi = 0; mi < 2; ++mi)
#pragma unroll
      for (int ni = 0; ni < 9; ++ni)
        acc[mi][ni] = __builtin_amdgcn_mfma_f32_16x16x32_bf16(
            af[mi], bf[ni], acc[mi][ni], 0, 0, 0);
    __syncthreads();
  }

  const float S_[3] = {100.f, 50.f, 25.f};
  const int Wl_[3] = {100, 50, 25};
  const int loff_[3] = {0, 10000, 12500};
#pragma unroll
  for (int cc = 0; cc < 2; ++cc) {
    if ((rg >> 1) == cc) {
      float* pan = (rg & 1) ? panel1 : panel0;
#pragma unroll
      for (int mi = 0; mi < 2; ++mi)
#pragma unroll
        for (int ni = 0; ni < 9; ++ni) {
          const int col = cg * 144 + ni * 16 + l15;
          const float bb = bias[col];
          const int rl = mi * 16 + lhi * 4;
#pragma unroll
          for (int r = 0; r < 4; ++r)
            pan[(rl + r) * 289 + col] = acc[mi][ni][r] + bb;
        }
    }
    __syncthreads();
    {
      const int rr = tid >> 3;          // 0..63 (rows within this round)
      const int h = tid & 7;
      const int g = r0 + cc * 64 + rr;
      if (g < M) {
        const float* rg_ = (rr < 32) ? &panel0[rr * 289]
                                     : &panel1[(rr - 32) * 289];
        float xy[24], lg[12];
#pragma unroll
        for (int j = 0; j < 24; ++j) xy[j] = rg_[h * 24 + j];
#pragma unroll
        for (int j = 0; j < 12; ++j) lg[j] = rg_[192 + h * 12 + j];
        float rx[3], ry[3];
#pragma unroll
        for (int l = 0; l < 3; ++l) {
          rx[l] = ref[(size_t)g * 6 + l * 2 + 0];
          ry[l] = ref[(size_t)g * 6 + l * 2 + 1];
        }
        float m = lg[0];
#pragma unroll
        for (int j = 1; j < 12; ++j) m = fmaxf(m, lg[j]);
        float e[12], s = 0.f;
#pragma unroll
        for (int j = 0; j < 12; ++j) { e[j] = __expf(lg[j] - m); s += e[j]; }
        const float inv = 1.f / s;

        uint out[36];
#pragma unroll
        for (int l = 0; l < 3; ++l) {
          const int Wl = Wl_[l];
#pragma unroll
          for (int p = 0; p < 4; ++p) {
            const int j = l * 4 + p;
            const float x = rx[l] * S_[l] + xy[l * 8 + p * 2 + 0] - 0.5f;
            const float y = ry[l] * S_[l] + xy[l * 8 + p * 2 + 1] - 0.5f;
            const float w = e[j] * inv;
            const float fx = floorf(x), fy = floorf(y);
            const int x0 = (int)fx, y0 = (int)fy;
            const float wx1 = x - fx, wy1 = y - fy;
            const float wx0 = 1.f - wx1, wy0 = 1.f - wy1;
            const int x0c = min(max(x0, 0), Wl - 1);
            const int x1c = min(max(x0 + 1, 0), Wl - 1);
            const int y0c = min(max(y0, 0), Wl - 1);
            const int y1c = min(max(y0 + 1, 0), Wl - 1);
            const float vx0 = (x0 >= 0 && x0 < Wl) ? wx0 : 0.f;
            const float vx1 = (x0 + 1 >= 0 && x0 + 1 < Wl) ? wx1 : 0.f;
            const float vy0 = (y0 >= 0 && y0 < Wl) ? wy0 : 0.f;
            const float vy1 = (y0 + 1 >= 0 && y0 + 1 < Wl) ? wy1 : 0.f;
            const uint base = (uint)(loff_[l] + y0c * Wl + x0c) * 64u;
            out[j * 3 + 0] = base | ((uint)(x1c - x0c) << 20)
                                  | ((uint)(y1c != y0c) << 21);
            out[j * 3 + 1] = (uint)f2h(w * vy0 * vx0) | ((uint)f2h(w * vy0 * vx1) << 16);
            out[j * 3 + 2] = (uint)f2h(w * vy1 * vx0) | ((uint)f2h(w * vy1 * vx1) << 16);
          }
        }
        uint4* o4 = (uint4*)(samp + (size_t)g * 288 + h * 36);
#pragma unroll
        for (int i = 0; i < 9; ++i)
          o4[i] = make_uint4(out[i * 4 + 0], out[i * 4 + 1],
                             out[i * 4 + 2], out[i * 4 + 3]);
      }
    }
    __syncthreads();
  }
}

// ---------------------------------------------------------------------------
// Output projection (round-19 proven): 128x256 tile, 512 threads, fp16 A via
// global_load_lds, fp16 B (WoT), f16 MFMA, fp32 C.
// ---------------------------------------------------------------------------
__global__ __launch_bounds__(512) void gemm_wide_o(
    const ushort* __restrict__ A16, const ushort* __restrict__ B_,
    const float* __restrict__ bias, float* __restrict__ C, int M) {
  __shared__ ushort As[4096];   // [128][32]
  __shared__ ushort Bs[8192];   // [256][32]
  const int tid = threadIdx.x;
  const int lane = tid & 63;
  const int wid = tid >> 6;
  const int wm = wid >> 2, wn = wid & 3;
  const int r0 = blockIdx.x * 128;
  const int l15 = lane & 15;
  const int lhi = lane >> 4;

  f32x4 acc[4][4] = {};

  for (int kk = 0; kk < 256; kk += 32) {
    {
      const int arow = min(r0 + wid * 16 + (lane >> 2), M - 1);
      gl_lds16(A16 + (size_t)arow * 256 + kk + (lane & 3) * 8,
               As + wid * 512);
    }
#pragma unroll
    for (int rr = 0; rr < 2; ++rr) {
      const int u = rr * 512 + tid;
      const int brow = u >> 2;
      gl_lds16(B_ + (size_t)brow * 256 + kk + (u & 3) * 8,
               Bs + rr * 4096 + wid * 512);
    }
    __syncthreads();

    f16x8 af[4], bf[4];
#pragma unroll
    for (int mi = 0; mi < 4; ++mi)
      af[mi] = *(const f16x8*)&As[(wm * 64 + mi * 16 + l15) * 32 + lhi * 8];
#pragma unroll
    for (int ni = 0; ni < 4; ++ni)
      bf[ni] = *(const f16x8*)&Bs[(wn * 64 + ni * 16 + l15) * 32 + lhi * 8];
#pragma unroll
    for (int mi = 0; mi < 4; ++mi)
#pragma unroll
      for (int ni = 0; ni < 4; ++ni)
        acc[mi][ni] = __builtin_amdgcn_mfma_f32_16x16x32_f16(
            af[mi], bf[ni], acc[mi][ni], 0, 0, 0);
    __syncthreads();
  }

#pragma unroll
  for (int ni = 0; ni < 4; ++ni) {
    const int col = wn * 64 + ni * 16 + l15;
    const float bb = bias[col];
#pragma unroll
    for (int mi = 0; mi < 4; ++mi) {
      const int rowb = r0 + wm * 64 + mi * 16 + lhi * 4;
#pragma unroll
      for (int r = 0; r < 4; ++r) {
        const int row = rowb + r;
        if (row < M) C[(size_t)row * 256 + col] = acc[mi][ni][r] + bb;
      }
    }
  }
}

// ---------------------------------------------------------------------------
// One-shot weight prep: transpose; Wv/Wc as bf16, Wo as FP16.
// ---------------------------------------------------------------------------
__global__ __launch_bounds__(256) void convert_W(
    const float* __restrict__ Wv, const float* __restrict__ Woff,
    const float* __restrict__ Watt, const float* __restrict__ Wo,
    const float* __restrict__ boff, const float* __restrict__ batt,
    ushort* __restrict__ WvT, ushort* __restrict__ WcT,
    ushort* __restrict__ WoT, float* __restrict__ bias288) {
  const int t = blockIdx.x * 256 + threadIdx.x;
  if (t < 256 * 256) {
    const int n = t >> 8, k = t & 255;
    WvT[t] = f2bf(Wv[k * 256 + n]);
    WoT[t] = f2h(Wo[k * 256 + n]);
  }
  if (t < 288 * 256) {
    const int n = t >> 8, k = t & 255;
    const float w = (n < 192) ? Woff[k * 192 + n] : Watt[k * 96 + (n - 192)];
    WcT[t] = f2bf(w);
  }
  if (t < 288) bias288[t] = (t < 192) ? boff[t] : batt[t - 192];
}

// ---------------------------------------------------------------------------
// v10 sample body (round-27/28 proven): SQ compile-time parity; byte-offset
// record decode (d0 = premult byte off | dx<<20 | dyValid<<21).
// ---------------------------------------------------------------------------
template <int SQ>
__device__ __forceinline__ void deform_body(
    const uint* __restrict__ rec, const char* __restrict__ vb, int xs,
    __half2& A0, __half2& A1, __half2& A2, __half2& A3) {
  const uint LB_[3] = {6400u, 3200u, 1600u};  // Wl*HD*2 per level
#pragma unroll
  for (int t = 0; t < 6; ++t) {
    const int j = 2 * t + SQ;                 // compile-time constant
    const uint d0 = rec[j * 3 + 0];
    const uint d1 = rec[j * 3 + 1];
    const uint d2 = rec[j * 3 + 2];
    const uint base = d0 & 0xFFFFFu;
    const uint offA = base + (xs ? ((d0 >> 14) & 64u) : 0u);
    const uint offB = offA + ((d0 & (1u << 21)) ? LB_[j >> 2] : 0u);
    const uint4 c0 = *(const uint4*)(vb + offA);
    const uint4 c1 = *(const uint4*)(vb + offB);
    const uint w0_ = xs ? (d1 >> 16) : (d1 & 0xffffu);
    const uint w1_ = xs ? (d2 >> 16) : (d2 & 0xffffu);
    const __half2 w0 = u2h2(w0_ | (w0_ << 16));
    const __half2 w1 = u2h2(w1_ | (w1_ << 16));
    A0 = __hfma2(w0, u2h2(c0.x), A0);
    A1 = __hfma2(w0, u2h2(c0.y), A1);
    A2 = __hfma2(w0, u2h2(c0.z), A2);
    A3 = __hfma2(w0, u2h2(c0.w), A3);
    A0 = __hfma2(w1, u2h2(c1.x), A0);
    A1 = __hfma2(w1, u2h2(c1.y), A1);
    A2 = __hfma2(w1, u2h2(c1.z), A2);
    A3 = __hfma2(w1, u2h2(c1.w), A3);
  }
}

// ---------------------------------------------------------------------------
// Bilinear sampling v10 (round-28 proven): 16 lanes per (g,h), LDS-staged
// records, parity-template bodies, byte-offset decode.
// Block = 16 queries x one pair; XCD partition: blockIdx = qchunk*32 + pair.
// ---------------------------------------------------------------------------
__global__ __launch_bounds__(256) void deform_packed(
    const ushort* __restrict__ vbf, const uint* __restrict__ samp,
    ushort* __restrict__ mid, int nq) {
  __shared__ __align__(16) uint recs[16][36];
  const int tid = threadIdx.x;
  const int pair = blockIdx.x & 31;          // b*8 + h
  const int qc = blockIdx.x >> 5;
  const int h = pair & 7;
  const int b = pair >> 3;
  const int q0 = qc * 16;

  // cooperative record staging: 144 uint4 (16 queries x 9)
  for (int i = tid; i < 144; i += 256) {
    const int qi = i / 9, di = (i - qi * 9) * 4;
    const int q = q0 + qi;
    if (q < nq)
      *(uint4*)&recs[qi][di] =
          *(const uint4*)&samp[((size_t)(b * nq + q)) * 288 + h * 36 + di];
  }
  __syncthreads();

  const int qi = tid >> 4;
  const int q = q0 + qi;
  if (q >= nq) return;
  const int lane16 = tid & 15;
  const int sq = lane16 >> 3;                // sample parity (0/1)
  const int xs = (lane16 >> 2) & 1;          // x-side
  const int cq = lane16 & 3;                 // channel quad (8 ch)
  const int g = b * nq + q;

  const char* vb = (const char*)(vbf + ((size_t)pair * nq) * HD + cq * 8);
  const uint* rec = recs[qi];

  __half2 A0 = __float2half2_rn(0.f), A1 = A0, A2 = A0, A3 = A0;
  if (sq == 0) deform_body<0>(rec, vb, xs, A0, A1, A2, A3);
  else         deform_body<1>(rec, vb, xs, A0, A1, A2, A3);

  // merge sample parities (lane^8), then x-sides (lane^4)
  A0 = __hadd2(A0, u2h2(__shfl_xor(h22u(A0), 8)));
  A1 = __hadd2(A1, u2h2(__shfl_xor(h22u(A1), 8)));
  A2 = __hadd2(A2, u2h2(__shfl_xor(h22u(A2), 8)));
  A3 = __hadd2(A3, u2h2(__shfl_xor(h22u(A3), 8)));
  A0 = __hadd2(A0, u2h2(__shfl_xor(h22u(A0), 4)));
  A1 = __hadd2(A1, u2h2(__shfl_xor(h22u(A1), 4)));
  A2 = __hadd2(A2, u2h2(__shfl_xor(h22u(A2), 4)));
  A3 = __hadd2(A3, u2h2(__shfl_xor(h22u(A3), 4)));

  if ((lane16 >> 2) == 0) {  // sq == 0 && xs == 0
    uint4 o;
    o.x = h22u(A0); o.y = h22u(A1); o.z = h22u(A2); o.w = h22u(A3);
    *(uint4*)&mid[(size_t)g * E + h * HD + cq * 8] = o;
  }
}

// ---------------------------------------------------------------------------
extern "C" void kernel_launch(void* const* d_in, const int* in_sizes, int n_in,
                              void* d_out, int out_size, void* d_ws, size_t ws_size,
                              hipStream_t stream) {
  const float* query = (const float*)d_in[0];
  const float* refpt = (const float*)d_in[1];
  const float* value = (const float*)d_in[2];
  const float* Wv   = (const float*)d_in[4];
  const float* bv   = (const float*)d_in[5];
  const float* Woff = (const float*)d_in[6];
  const float* boff = (const float*)d_in[7];
  const float* Watt = (const float*)d_in[8];
  const float* batt = (const float*)d_in[9];
  const float* Wo   = (const float*)d_in[10];
  const float* bo   = (const float*)d_in[11];

  const int M = in_sizes[0] / E;  // B * Lq = 52500
  const int nq = LQ;              // queries per batch
  const int nb = M / nq;          // B = 4

  // workspace layout (~90 MB)
  float* wsf   = (float*)d_ws;
  float* raw   = wsf;                         // M*288 dwords: packed samples
  float* b288  = raw + (size_t)M * 288;       // 288
  ushort* mid  = (ushort*)(b288 + 288);       // M*256 fp16
  ushort* vbf  = mid + (size_t)M * 256;       // M*256 fp16
  ushort* wvT  = vbf + (size_t)M * 256;       // 65536 bf16
  ushort* woT  = wvT + 65536;                 // 65536 fp16
  ushort* wcT  = woT + 65536;                 // 73728 bf16

  const int gridM = (M + 127) / 128;

  // 0. weight prep
  convert_W<<<288, 256, 0, stream>>>(Wv, Woff, Watt, Wo, boff, batt,
                                     wvT, wcT, woT, b288);
  // 1. value projection (512-thr wide, round-19 proven) -> vbf (fp16)
  gemm_wide_v<<<gridM, 512, 0, stream>>>(value, wvT, bv, vbf, M);
  // 2. fused offsets+attention GEMM + double-panel pack -> samp
  gemm_q_pack<<<gridM, 512, 0, stream>>>(
      query, wcT, b288, refpt, (uint*)raw, M);
  // 3. deformable bilinear sampling v10 (round-28 proven), XCD-partitioned
  const int qchunks = (nq + 15) / 16;
  deform_packed<<<qchunks * 32, 256, 0, stream>>>(
      vbf, (const uint*)raw, mid, nq);
  // 4. output projection (512-thr wide, round-19 proven) -> d_out (fp32)
  gemm_wide_o<<<gridM, 512, 0, stream>>>(mid, woT, bo, (float*)d_out, M);
}